// Round 3
// baseline (861.599 us; speedup 1.0000x reference)
//
#include <hip/hip_runtime.h>

#define NIMG 16
#define NC 3
#define H 256
#define W 256
#define HW (H * W)
#define NS 25          // 5x5 per-pixel kernel
#define TH 32
#define TW 32
#define SRH (TH + 10)  // avg/max region: fac halo(2) + conv halo(3) each side
#define SRW (TW + 10)
#define MRH (TH + 4)   // q region: fac halo(2) each side
#define MRW (TW + 4)
#define NTHREADS 256
#define PPT ((TH * TW) / NTHREADS)  // 4

// out = blur_info  (the "sharp" center term, folded; branches atomically add the rest)
__global__ __launch_bounds__(256)
void init_out(const float4* __restrict__ bi, float4* __restrict__ out, int n4) {
    int i = blockIdx.x * 256 + threadIdx.x;
    if (i < n4) out[i] = bi[i];
}

__global__ __launch_bounds__(NTHREADS, 5)
void reblur_branch(const float* __restrict__ blur_info,
                   const float* __restrict__ pp0,
                   const float* __restrict__ pp1,
                   const float* __restrict__ pp2,
                   const float* __restrict__ wt0,
                   const float* __restrict__ wt1,
                   const float* __restrict__ wt2,
                   float* __restrict__ out)
{
    __shared__ float s_avg[SRH * SRW];   // 7.1 KB (channel-sum, 1/25 folded into wts)
    __shared__ float s_mx[SRH * SRW];    // 7.1 KB
    __shared__ float q[NC][MRH * MRW];   // 15.6 KB  q = mask*blur
    __shared__ float wts[98];            // this branch's conv weights

    const int tid = threadIdx.x;
    const int z  = blockIdx.z;
    const int b  = z >> 4;               // branch slowest in dispatch order -> L3 phase lock
    const int n  = z & 15;
    const int h0 = blockIdx.y * TH;
    const int w0 = blockIdx.x * TW;

    const float* wp = (b == 0) ? wt0 : (b == 1) ? wt1 : wt2;
    const float* pp = ((b == 0) ? pp0 : (b == 1) ? pp1 : pp2) + n * (NS * HW);

    for (int i = tid; i < 98; i += NTHREADS)
        wts[i] = wp[i] * (i < 49 ? 0.04f : 1.0f);   // fold 1/25 avg into weights

    // ---- step 1: channel sum & max over 42x42 halo region
    for (int i = tid; i < SRH * SRW; i += NTHREADS) {
        int rr = i / SRW, cc = i % SRW;
        int gh = h0 - 5 + rr, gw = w0 - 5 + cc;
        float sum = 0.f, mx = 0.f;   // out-of-image => conv zero-padding of [avg,max]
        if ((unsigned)gh < H && (unsigned)gw < W) {
            const float* p = pp + gh * W + gw;
            float v0 = p[0];
            sum = v0; mx = v0;
            #pragma unroll
            for (int s = 1; s < NS; ++s) {
                float v = p[s * HW];
                sum += v; mx = fmaxf(mx, v);
            }
        }
        s_avg[i] = sum;
        s_mx[i]  = mx;
    }
    __syncthreads();   // covers wts too

    // ---- step 2: 7x7 conv + sigmoid -> mask; q = mask * blur over 36x36 region.
    for (int wi = tid; wi < (MRH / 4) * MRW; wi += NTHREADS) {
        int rb = wi / MRW, cc = wi % MRW;
        int r0 = rb * 4;
        float a4[4] = {0.f, 0.f, 0.f, 0.f};
        #pragma unroll
        for (int j = 0; j < 10; ++j) {   // 10 input rows cover 4 outputs
            float av[7], mv[7];
            #pragma unroll
            for (int t = 0; t < 7; ++t) {
                av[t] = s_avg[(r0 + j) * SRW + cc + t];
                mv[t] = s_mx[(r0 + j) * SRW + cc + t];
            }
            const int klo = (j - 6) > 0 ? (j - 6) : 0;
            const int khi = j < 3 ? j : 3;
            #pragma unroll
            for (int k = klo; k <= khi; ++k) {
                const int wr = (j - k) * 7;
                #pragma unroll
                for (int t = 0; t < 7; ++t)
                    a4[k] += av[t] * wts[wr + t] + mv[t] * wts[49 + wr + t];
            }
        }
        #pragma unroll
        for (int k = 0; k < 4; ++k) {
            float m = 1.f / (1.f + __expf(-a4[k]));
            int gh = h0 - 2 + r0 + k, gw = w0 - 2 + cc;
            bool inb = (unsigned)gh < H && (unsigned)gw < W;
            int gi = gh * W + gw;
            #pragma unroll
            for (int c = 0; c < NC; ++c) {
                float bv = inb ? blur_info[(n * NC + c) * HW + gi] : 0.f;  // feat zero-pad
                q[c][(r0 + k) * MRW + cc] = m * bv;
            }
        }
    }
    __syncthreads();

    // ---- step 3: acc = -q_center + sum_s pk_s * q_s ; atomically add acc/3 to out.
    const float inv3 = 1.f / 3.f;
    for (int k = 0; k < PPT; ++k) {
        int oi = tid + k * NTHREADS;
        int r = oi / TW, cc = oi % TW;
        const float* pk = pp + (h0 + r) * W + (w0 + cc);
        float pkv[NS];
        #pragma unroll
        for (int s = 0; s < NS; ++s) pkv[s] = pk[s * HW];   // L3-warm from step 1 (phase-locked)
        int qc = (r + 2) * MRW + cc + 2;
        float f0 = -q[0][qc], f1 = -q[1][qc], f2 = -q[2][qc];
        #pragma unroll
        for (int s = 0; s < NS; ++s) {
            const int dh = s / 5, dw = s % 5;
            const int qi = (r + dh) * MRW + cc + dw;
            f0 += pkv[s] * q[0][qi];
            f1 += pkv[s] * q[1][qi];
            f2 += pkv[s] * q[2][qi];
        }
        int gi = (h0 + r) * W + (w0 + cc);
        unsafeAtomicAdd(&out[(n * NC + 0) * HW + gi], f0 * inv3);
        unsafeAtomicAdd(&out[(n * NC + 1) * HW + gi], f1 * inv3);
        unsafeAtomicAdd(&out[(n * NC + 2) * HW + gi], f2 * inv3);
    }
}

extern "C" void kernel_launch(void* const* d_in, const int* in_sizes, int n_in,
                              void* d_out, int out_size, void* d_ws, size_t ws_size,
                              hipStream_t stream) {
    const float* blur = (const float*)d_in[0];
    float* out = (float*)d_out;

    int n4 = out_size / 4;   // 3,145,728 / 4
    init_out<<<(n4 + 255) / 256, 256, 0, stream>>>((const float4*)blur, (float4*)out, n4);

    dim3 grid(W / TW, H / TH, NIMG * 3);   // 8 x 8 x 48 = 3072 blocks, branch-major z
    reblur_branch<<<grid, NTHREADS, 0, stream>>>(
        blur,
        (const float*)d_in[1], (const float*)d_in[2], (const float*)d_in[3],
        (const float*)d_in[4], (const float*)d_in[5], (const float*)d_in[6],
        out);
}

// Round 4
// 700.734 us; speedup vs baseline: 1.2296x; 1.2296x over previous
//
#include <hip/hip_runtime.h>

#define NIMG 16
#define NC 3
#define H 256
#define W 256
#define HW (H * W)
#define NS 25          // 5x5 per-pixel kernel
#define TH 32
#define TW 32
#define SRH (TH + 10)  // avg/max region: fac halo(2) + conv halo(3) each side
#define SRW (TW + 10)
#define MRH (TH + 4)   // q region: fac halo(2) each side
#define MRW (TW + 4)
#define NTHREADS 1024  // 1 output pixel per thread

// Register discipline: NO per-thread arrays anywhere (R2/R3's pkv[25] caused
// scratch spills -> ~1 GB of scratch HBM traffic, WRITE_SIZE 45x output size).
// Every phase streams load->use->discard; target <=64 VGPR for 2 blocks/CU.
__global__ __launch_bounds__(NTHREADS, 8)
void reblur_fused(const float* __restrict__ blur_info,
                  const float* __restrict__ pp0,
                  const float* __restrict__ pp1,
                  const float* __restrict__ pp2,
                  const float* __restrict__ wt0,
                  const float* __restrict__ wt1,
                  const float* __restrict__ wt2,
                  float* __restrict__ out)
{
    __shared__ float s_avg[SRH * SRW];          // 7.1 KB (channel-sum; 1/25 in wts)
    __shared__ float s_mx[SRH * SRW];           // 7.1 KB
    __shared__ float q[NC][MRH * MRW];          // 15.6 KB  q = mask*blur
    __shared__ float blur_l[NC][MRH * MRW];     // 15.6 KB  blur tile (+-2 halo), reused x3
    __shared__ float wts[3][98];                // ~47 KB total -> 2 blocks/CU

    const int tid = threadIdx.x;
    const int n  = blockIdx.z;
    const int h0 = blockIdx.y * TH;
    const int w0 = blockIdx.x * TW;

    for (int i = tid; i < 3 * 98; i += NTHREADS) {
        int b = i / 98, j = i % 98;
        const float* wp = (b == 0) ? wt0 : (b == 1) ? wt1 : wt2;
        wts[b][j] = wp[j] * (j < 49 ? 0.04f : 1.0f);   // fold 1/25 avg into weights
    }
    for (int i = tid; i < NC * MRH * MRW; i += NTHREADS) {
        int c  = i / (MRH * MRW);
        int rr = (i / MRW) % MRH;
        int cc = i % MRW;
        int gh = h0 - 2 + rr, gw = w0 - 2 + cc;
        float v = 0.f;                          // feat zero-pad outside image
        if ((unsigned)gh < H && (unsigned)gw < W)
            v = blur_info[(n * NC + c) * HW + gh * W + gw];
        blur_l[c][rr * MRW + cc] = v;
    }

    const int r  = tid >> 5;     // this thread's output pixel in the 32x32 tile
    const int cc = tid & 31;
    float acc0 = 0.f, acc1 = 0.f, acc2 = 0.f;

    for (int b = 0; b < 3; ++b) {
        const float* pp = ((b == 0) ? pp0 : (b == 1) ? pp1 : pp2) + n * (NS * HW);

        // ---- step 1: channel sum & max over 42x42 halo region (~1.7 px/thread)
        for (int i = tid; i < SRH * SRW; i += NTHREADS) {
            int rr = i / SRW, c2 = i % SRW;
            int gh = h0 - 5 + rr, gw = w0 - 5 + c2;
            float sum = 0.f, mx = 0.f;          // OOB => zero-padded [avg,max]
            if ((unsigned)gh < H && (unsigned)gw < W) {
                const float* p = pp + gh * W + gw;
                float v0 = p[0];
                sum = v0; mx = v0;
                #pragma unroll
                for (int s = 1; s < NS; ++s) {
                    float v = p[s * HW];
                    sum += v; mx = fmaxf(mx, v);
                }
            }
            s_avg[i] = sum;
            s_mx[i]  = mx;
        }
        __syncthreads();   // also covers wts/blur_l on first branch

        // ---- step 2: 7x7 conv + sigmoid -> mask; q = mask*blur, 36x36 region.
        // One mask pixel per item, streaming taps (no held rows -> no spills).
        for (int i = tid; i < MRH * MRW; i += NTHREADS) {
            int rr = i / MRW, c2 = i % MRW;
            float a = 0.f;
            #pragma unroll
            for (int j = 0; j < 7; ++j) {
                #pragma unroll
                for (int t = 0; t < 7; ++t) {
                    int si = (rr + j) * SRW + c2 + t;
                    a += s_avg[si] * wts[b][j * 7 + t]
                       + s_mx[si]  * wts[b][49 + j * 7 + t];
                }
            }
            float m = 1.f / (1.f + __expf(-a));
            q[0][i] = m * blur_l[0][i];
            q[1][i] = m * blur_l[1][i];
            q[2][i] = m * blur_l[2][i];
        }
        __syncthreads();

        // ---- step 3: acc += -q_center + sum_s pk_s * q_s (load->FMA->discard)
        {
            const float* pk = pp + (h0 + r) * W + (w0 + cc);
            int qc = (r + 2) * MRW + cc + 2;
            float f0 = -q[0][qc], f1 = -q[1][qc], f2 = -q[2][qc];
            #pragma unroll
            for (int s = 0; s < NS; ++s) {
                const int qi = (r + s / 5) * MRW + cc + (s % 5);
                float v = pk[s * HW];           // L3-warm from step 1
                f0 += v * q[0][qi];
                f1 += v * q[1][qi];
                f2 += v * q[2][qi];
            }
            acc0 += f0; acc1 += f1; acc2 += f2;
        }
        // No barrier needed: next step-2 q-write is fenced behind next step-1's
        // barrier, which requires all threads to have finished this step 3.
    }

    const float inv3 = 1.f / 3.f;
    const int qc = (r + 2) * MRW + cc + 2;
    const int gi = (h0 + r) * W + (w0 + cc);
    out[(n * NC + 0) * HW + gi] = blur_l[0][qc] + acc0 * inv3;
    out[(n * NC + 1) * HW + gi] = blur_l[1][qc] + acc1 * inv3;
    out[(n * NC + 2) * HW + gi] = blur_l[2][qc] + acc2 * inv3;
}

extern "C" void kernel_launch(void* const* d_in, const int* in_sizes, int n_in,
                              void* d_out, int out_size, void* d_ws, size_t ws_size,
                              hipStream_t stream) {
    dim3 grid(W / TW, H / TH, NIMG);   // 8 x 8 x 16 = 1024 blocks of 1024 threads
    reblur_fused<<<grid, NTHREADS, 0, stream>>>(
        (const float*)d_in[0],
        (const float*)d_in[1], (const float*)d_in[2], (const float*)d_in[3],
        (const float*)d_in[4], (const float*)d_in[5], (const float*)d_in[6],
        (float*)d_out);
}

// Round 5
// 390.871 us; speedup vs baseline: 2.2043x; 1.7928x over previous
//
#include <hip/hip_runtime.h>

#define NIMG 16
#define NC 3
#define H 256
#define W 256
#define HW (H * W)
#define NS 25          // 5x5 per-pixel kernel
#define TH 32
#define TW 32
#define SRH (TH + 10)  // s-tile region: fac halo(2) + conv halo(3) each side
#define SRW (TW + 10)
#define MRH (TH + 4)   // q region: fac halo(2) each side
#define MRW (TW + 4)
#define NTHREADS 256
#define PPT ((TH * TW) / NTHREADS)  // 4

// round-to-nearest-even fp32 -> bf16 (as u16)
__device__ __forceinline__ unsigned bf16r(float x) {
    union { float f; unsigned u; } c; c.f = x;
    return (c.u + 0x7FFFu + ((c.u >> 16) & 1u)) >> 16;
}
__device__ __forceinline__ float bf_hi(unsigned u) {  // high 16 bits -> float
    union { unsigned u; float f; } c; c.u = u & 0xFFFF0000u; return c.f;
}
__device__ __forceinline__ float bf_lo(unsigned u) {  // low 16 bits -> float
    union { unsigned u; float f; } c; c.u = u << 16; return c.f;
}

// ---- Kernel A: pointwise channel sum+max of one branch's perpix tensor.
// Perfectly coalesced, no halo, no barriers. Packs (sum, max) as 2xbf16.
__global__ __launch_bounds__(256)
void reduce_s(const float* __restrict__ pp, unsigned* __restrict__ s_ws) {
    const int n   = blockIdx.y;
    const int pix = blockIdx.x * 256 + threadIdx.x;
    const float* p = pp + n * (NS * HW) + pix;
    float v = p[0];
    float sum = v, mx = v;
    #pragma unroll
    for (int s = 1; s < NS; ++s) {
        float x = p[s * HW];
        sum += x; mx = fmaxf(mx, x);
    }
    s_ws[n * HW + pix] = (bf16r(sum) << 16) | bf16r(mx);
}

// ---- Kernel B: conv7x7(s)+sigmoid -> q=mask*blur in LDS -> per-pixel 5x5 fac,
// accumulate into out. perpix center re-read is L3-warm (A_b just streamed it).
__global__ __launch_bounds__(NTHREADS)
void reblur_bc(const float* __restrict__ blur_info,
               const float* __restrict__ pp,
               const unsigned* __restrict__ s_ws,
               const float* __restrict__ wt,
               float* __restrict__ out,
               int first)
{
    __shared__ unsigned s_l[SRH * SRW];      // 7.1 KB packed (sum,max)
    __shared__ float q[NC][MRH * MRW];       // 15.6 KB  q = mask*blur
    __shared__ float wts[98];

    const int tid = threadIdx.x;
    const int n  = blockIdx.z;
    const int h0 = blockIdx.y * TH;
    const int w0 = blockIdx.x * TW;

    for (int i = tid; i < 98; i += NTHREADS)
        wts[i] = wt[i] * (i < 49 ? 0.04f : 1.0f);   // fold 1/25 avg into weights

    // s tile with +-5 halo; OOB -> 0 (bf16 zero == conv zero-padding of [avg,max])
    for (int i = tid; i < SRH * SRW; i += NTHREADS) {
        int rr = i / SRW, cc = i % SRW;
        int gh = h0 - 5 + rr, gw = w0 - 5 + cc;
        unsigned u = 0;
        if ((unsigned)gh < H && (unsigned)gw < W)
            u = s_ws[n * HW + gh * W + gw];
        s_l[i] = u;
    }
    __syncthreads();

    // conv + sigmoid -> mask; q = mask*blur over 36x36 (streaming taps, no arrays)
    for (int i = tid; i < MRH * MRW; i += NTHREADS) {
        int rr = i / MRW, cc = i % MRW;
        float a = 0.f;
        #pragma unroll
        for (int j = 0; j < 7; ++j) {
            #pragma unroll
            for (int t = 0; t < 7; ++t) {
                unsigned u = s_l[(rr + j) * SRW + cc + t];
                a += bf_hi(u) * wts[j * 7 + t] + bf_lo(u) * wts[49 + j * 7 + t];
            }
        }
        float m = 1.f / (1.f + __expf(-a));
        int gh = h0 - 2 + rr, gw = w0 - 2 + cc;
        bool inb = (unsigned)gh < H && (unsigned)gw < W;
        int gi = gh * W + gw;
        #pragma unroll
        for (int c = 0; c < NC; ++c) {
            float bv = inb ? blur_info[(n * NC + c) * HW + gi] : 0.f;  // feat zero-pad
            q[c][i] = m * bv;
        }
    }
    __syncthreads();

    // fac + accumulate: out (+)= (-q_center + sum_s pk_s * q_s)/3
    const float inv3 = 1.f / 3.f;
    for (int k = 0; k < PPT; ++k) {
        int oi = tid + k * NTHREADS;
        int r = oi / TW, cc = oi % TW;
        const float* pk = pp + n * (NS * HW) + (h0 + r) * W + (w0 + cc);
        int qc = (r + 2) * MRW + cc + 2;
        float f0 = -q[0][qc], f1 = -q[1][qc], f2 = -q[2][qc];
        #pragma unroll
        for (int s = 0; s < NS; ++s) {
            const int qi = (r + s / 5) * MRW + cc + (s % 5);
            float v = pk[s * HW];            // L3-warm: A_b streamed this 20us ago
            f0 += v * q[0][qi];
            f1 += v * q[1][qi];
            f2 += v * q[2][qi];
        }
        int gi = (h0 + r) * W + (w0 + cc);
        if (first) {
            out[(n * NC + 0) * HW + gi] = blur_info[(n * NC + 0) * HW + gi] + f0 * inv3;
            out[(n * NC + 1) * HW + gi] = blur_info[(n * NC + 1) * HW + gi] + f1 * inv3;
            out[(n * NC + 2) * HW + gi] = blur_info[(n * NC + 2) * HW + gi] + f2 * inv3;
        } else {
            out[(n * NC + 0) * HW + gi] += f0 * inv3;
            out[(n * NC + 1) * HW + gi] += f1 * inv3;
            out[(n * NC + 2) * HW + gi] += f2 * inv3;
        }
    }
}

extern "C" void kernel_launch(void* const* d_in, const int* in_sizes, int n_in,
                              void* d_out, int out_size, void* d_ws, size_t ws_size,
                              hipStream_t stream) {
    const float* blur = (const float*)d_in[0];
    float* out = (float*)d_out;
    unsigned* s_ws = (unsigned*)d_ws;        // 16*HW u32 = 4.2 MB, reused per branch

    dim3 gridA(HW / 256, NIMG);              // 256 x 16 pointwise blocks
    dim3 gridB(W / TW, H / TH, NIMG);        // 8 x 8 x 16 tiles

    for (int b = 0; b < 3; ++b) {
        const float* pp = (const float*)d_in[1 + b];
        const float* wt = (const float*)d_in[4 + b];
        reduce_s<<<gridA, 256, 0, stream>>>(pp, s_ws);
        reblur_bc<<<gridB, NTHREADS, 0, stream>>>(blur, pp, s_ws, wt, out, b == 0);
    }
}